// Round 1
// baseline (8393.221 us; speedup 1.0000x reference)
//
#include <hip/hip_runtime.h>
#include <hip/hip_fp16.h>

// Geometry
#define HH 540
#define WW 960
#define HWPIX (HH*WW)   // 518400

// Workspace layout (per-batch staging, fp16 channels-last):
//   f1: HWPIX*64*2 = 66,355,200 B
//   f2: HWPIX*32*2 = 33,177,600 B
//   f3: HWPIX*32*2 = 33,177,600 B
//   total 132,710,400 B

__device__ __forceinline__ void load8h(const __half* __restrict__ p, bool ok, float a[8]) {
    if (ok) {
        int4 v = *reinterpret_cast<const int4*>(p);   // 8 halfs, 16B aligned
        const __half2* h2 = reinterpret_cast<const __half2*>(&v);
#pragma unroll
        for (int i = 0; i < 4; i++) {
            float2 f = __half22float2(h2[i]);
            a[2*i] = f.x; a[2*i+1] = f.y;
        }
    } else {
#pragma unroll
        for (int i = 0; i < 8; i++) a[i] = 0.f;
    }
}

// conv1: 1->64, 5x5, pad 2, PReLU. One pixel/thread, all 64 channels.
__global__ __launch_bounds__(256) void conv1_k(const float* __restrict__ xin,
        const float* __restrict__ wg, const float* __restrict__ bg,
        const float* __restrict__ pa, __half* __restrict__ f1) {
    __shared__ float lw[25*64];   // [tap][co]
    __shared__ float lb[64];
    const int tid = threadIdx.x;
    for (int i = tid; i < 25*64; i += 256) {
        int t = i >> 6, co = i & 63;
        lw[i] = wg[co*25 + t];     // conv1_w is (64,1,5,5)
    }
    if (tid < 64) lb[tid] = bg[tid];
    __syncthreads();
    int idx = blockIdx.x*256 + tid;
    if (idx >= HWPIX) return;
    const float alpha = pa[0];
    int y = idx / WW, x = idx - y*WW;
    float patch[25];
#pragma unroll
    for (int ky = 0; ky < 5; ky++) {
        int yy = y + ky - 2;
        bool yok = (unsigned)yy < (unsigned)HH;
#pragma unroll
        for (int kx = 0; kx < 5; kx++) {
            int xx = x + kx - 2;
            patch[ky*5+kx] = (yok && (unsigned)xx < (unsigned)WW) ? xin[yy*WW + xx] : 0.f;
        }
    }
    float acc[64];
#pragma unroll
    for (int c = 0; c < 64; c++) acc[c] = lb[c];
#pragma unroll
    for (int t = 0; t < 25; t++) {
        float p = patch[t];
        const float4* wv = reinterpret_cast<const float4*>(&lw[t*64]);
#pragma unroll
        for (int q = 0; q < 16; q++) {
            float4 w4 = wv[q];
            acc[q*4+0] += p*w4.x; acc[q*4+1] += p*w4.y;
            acc[q*4+2] += p*w4.z; acc[q*4+3] += p*w4.w;
        }
    }
    __half hb[64];
#pragma unroll
    for (int c = 0; c < 64; c++) {
        float v = acc[c];
        v = (v >= 0.f) ? v : alpha*v;
        hb[c] = __float2half(v);
    }
    int4* dst = reinterpret_cast<int4*>(f1 + (size_t)idx*64);
    const int4* src = reinterpret_cast<const int4*>(hb);
#pragma unroll
    for (int i = 0; i < 8; i++) dst[i] = src[i];
}

// conv2/conv3: CI->32, 3x3, pad 1, PReLU. COB output channels per block
// (blockIdx.y selects the channel slice), PIX x-adjacent pixels per thread.
// Weights in LDS as [tap][ci][cob] (fp32) -> broadcast ds_read_b128 inner loop.
template<int CI, int COB, int PIX>
__global__ __launch_bounds__(256) void convB_k(const __half* __restrict__ fin,
        const float* __restrict__ wg, const float* __restrict__ bg,
        const float* __restrict__ pa, __half* __restrict__ fout) {
    __shared__ float lw[9*CI*COB];
    const int tid = threadIdx.x;
    const int coff = blockIdx.y * COB;
    for (int i = tid; i < 9*CI*COB; i += 256) {
        int tap = i / (CI*COB);
        int r   = i - tap*(CI*COB);
        int ci  = r / COB;
        int co  = r - ci*COB;
        lw[i] = wg[((coff+co)*CI + ci)*9 + tap];   // w is (32, CI, 3, 3)
    }
    __syncthreads();
    int pidx = (blockIdx.x*256 + tid)*PIX;
    if (pidx >= HWPIX) return;            // WW%PIX==0 -> quads never cross rows
    const float alpha = pa[0];
    int y = pidx / WW, x = pidx - y*WW;
    float acc[PIX][COB];
#pragma unroll
    for (int p = 0; p < PIX; p++)
#pragma unroll
        for (int c = 0; c < COB; c++) acc[p][c] = bg[coff+c];
#pragma unroll
    for (int ky = 0; ky < 3; ky++) {
        int yy = y + ky - 1;
        bool yok = (unsigned)yy < (unsigned)HH;
        const __half* rowp = fin + (size_t)yy*WW*CI;
#pragma unroll
        for (int kx = 0; kx < 3; kx++) {
            const float* wt = &lw[(ky*3+kx)*CI*COB];
            for (int c8 = 0; c8 < CI; c8 += 8) {
                float a[PIX][8];
#pragma unroll
                for (int p = 0; p < PIX; p++) {
                    int xx = x + p + kx - 1;
                    bool ok = yok && (unsigned)xx < (unsigned)WW;
                    load8h(rowp + xx*CI + c8, ok, a[p]);
                }
#pragma unroll
                for (int j = 0; j < 8; j++) {
                    const float4* wv = reinterpret_cast<const float4*>(&wt[(c8+j)*COB]);
#pragma unroll
                    for (int q = 0; q < COB/4; q++) {
                        float4 w4 = wv[q];
#pragma unroll
                        for (int p = 0; p < PIX; p++) {
                            acc[p][q*4+0] += a[p][j]*w4.x;
                            acc[p][q*4+1] += a[p][j]*w4.y;
                            acc[p][q*4+2] += a[p][j]*w4.z;
                            acc[p][q*4+3] += a[p][j]*w4.w;
                        }
                    }
                }
            }
        }
    }
#pragma unroll
    for (int p = 0; p < PIX; p++) {
        __half hb[COB];
#pragma unroll
        for (int c = 0; c < COB; c++) {
            float v = acc[p][c];
            v = (v >= 0.f) ? v : alpha*v;
            hb[c] = __float2half(v);
        }
        int4* dst = reinterpret_cast<int4*>(fout + (size_t)(pidx+p)*32 + coff);
        const int4* src = reinterpret_cast<const int4*>(hb);
#pragma unroll
        for (int i = 0; i < COB/8; i++) dst[i] = src[i];
    }
}

// conv4 (32->37, 3x3, pad 1, +bias, NO prelu) fused with the pixel-shuffle head.
// COORS rows: k0=(-.25,.25) k1=(.25,.25) k2=(-.25,-.25) k3=(.25,-.25)
// h_k,j = relu(COORS[k,0]*W[2j] + COORS[k,1]*W[2j+1]); out_k = sum_j h*W[24+j] + W[36]
// out[b,0,2y+ky,2x+kx] = out_{k=ky*2+kx}[y,x]
__global__ __launch_bounds__(256) void conv4_k(const __half* __restrict__ fin,
        const float* __restrict__ wg, const float* __restrict__ bg,
        float* __restrict__ outp) {
    __shared__ float lw[9*32*40];   // [tap][ci][co padded to 40]
    const int tid = threadIdx.x;
    for (int i = tid; i < 9*32*40; i += 256) {
        int tap = i / 1280;
        int r   = i - tap*1280;
        int ci  = r / 40;
        int co  = r - ci*40;
        lw[i] = (co < 37) ? wg[(co*32 + ci)*9 + tap] : 0.f;
    }
    __syncthreads();
    int pidx = (blockIdx.x*256 + tid)*2;
    if (pidx >= HWPIX) return;
    int y = pidx / WW, x = pidx - y*WW;
    float acc[2][37];
#pragma unroll
    for (int p = 0; p < 2; p++)
#pragma unroll
        for (int c = 0; c < 37; c++) acc[p][c] = bg[c];
#pragma unroll
    for (int ky = 0; ky < 3; ky++) {
        int yy = y + ky - 1;
        bool yok = (unsigned)yy < (unsigned)HH;
        const __half* rowp = fin + (size_t)yy*WW*32;
#pragma unroll
        for (int kx = 0; kx < 3; kx++) {
            const float* wt = &lw[(ky*3+kx)*32*40];
            for (int c8 = 0; c8 < 32; c8 += 8) {
                float a[2][8];
#pragma unroll
                for (int p = 0; p < 2; p++) {
                    int xx = x + p + kx - 1;
                    bool ok = yok && (unsigned)xx < (unsigned)WW;
                    load8h(rowp + xx*32 + c8, ok, a[p]);
                }
#pragma unroll
                for (int j = 0; j < 8; j++) {
                    const float* wrow = &wt[(c8+j)*40];
#pragma unroll
                    for (int q = 0; q < 9; q++) {
                        float4 w4 = reinterpret_cast<const float4*>(wrow)[q];
#pragma unroll
                        for (int p = 0; p < 2; p++) {
                            acc[p][q*4+0] += a[p][j]*w4.x;
                            acc[p][q*4+1] += a[p][j]*w4.y;
                            acc[p][q*4+2] += a[p][j]*w4.z;
                            acc[p][q*4+3] += a[p][j]*w4.w;
                        }
                    }
                    float w36 = wrow[36];
#pragma unroll
                    for (int p = 0; p < 2; p++) acc[p][36] += a[p][j]*w36;
                }
            }
        }
    }
    float r0[4], r1[4];
#pragma unroll
    for (int p = 0; p < 2; p++) {
        float base = acc[p][36];
        float o0 = base, o1 = base, o2 = base, o3 = base;
#pragma unroll
        for (int j = 0; j < 12; j++) {
            float u  = acc[p][2*j];
            float v  = acc[p][2*j+1];
            float w1 = acc[p][24+j];
            float s = 0.25f*(u+v);   // k1 pre-act;  k2 = -s
            float d = 0.25f*(v-u);   // k0 pre-act;  k3 = -d
            o0 += fmaxf(d, 0.f)*w1;
            o1 += fmaxf(s, 0.f)*w1;
            o2 += fmaxf(-s, 0.f)*w1;
            o3 += fmaxf(-d, 0.f)*w1;
        }
        r0[p*2+0] = o0; r0[p*2+1] = o1;
        r1[p*2+0] = o2; r1[p*2+1] = o3;
    }
    // pixels x (even) and x+1 -> output cols 2x..2x+3, rows 2y and 2y+1
    int orow = 2*y, ocol = 2*x;
    *reinterpret_cast<float4*>(outp + (size_t)orow*(2*WW) + ocol)
        = make_float4(r0[0], r0[1], r0[2], r0[3]);
    *reinterpret_cast<float4*>(outp + (size_t)(orow+1)*(2*WW) + ocol)
        = make_float4(r1[0], r1[1], r1[2], r1[3]);
}

extern "C" void kernel_launch(void* const* d_in, const int* in_sizes, int n_in,
                              void* d_out, int out_size, void* d_ws, size_t ws_size,
                              hipStream_t stream) {
    const float* x  = (const float*)d_in[0];
    const float* w1 = (const float*)d_in[1];
    const float* b1 = (const float*)d_in[2];
    const float* w2 = (const float*)d_in[3];
    const float* b2 = (const float*)d_in[4];
    const float* w3 = (const float*)d_in[5];
    const float* b3 = (const float*)d_in[6];
    const float* w4 = (const float*)d_in[7];
    const float* b4 = (const float*)d_in[8];
    const float* pa = (const float*)d_in[9];
    float* outp = (float*)d_out;

    char* ws = (char*)d_ws;
    __half* f1 = (__half*)(ws);                            // 66,355,200 B
    __half* f2 = (__half*)(ws + 66355200);                 // 33,177,600 B
    __half* f3 = (__half*)(ws + 66355200 + 33177600);      // 33,177,600 B

    const int HWp = HWPIX;
    for (int b = 0; b < 4; b++) {
        conv1_k<<<dim3((HWp + 255)/256), 256, 0, stream>>>(
            x + (size_t)b*HWp, w1, b1, pa, f1);
        // conv2: CI=64, 16 out-ch per block (LDS 36.9KB), 4 px/thread
        convB_k<64,16,4><<<dim3((HWp + 1023)/1024, 2), 256, 0, stream>>>(
            f1, w2, b2, pa, f2);
        // conv3: CI=32, all 32 out-ch (LDS 36.9KB), 2 px/thread
        convB_k<32,32,2><<<dim3((HWp + 511)/512, 1), 256, 0, stream>>>(
            f2, w3, b3, pa, f3);
        conv4_k<<<dim3((HWp + 511)/512), 256, 0, stream>>>(
            f3, w4, b4, outp + (size_t)b*4*HWp);
    }
}

// Round 2
// 923.058 us; speedup vs baseline: 9.0928x; 9.0928x over previous
//
#include <hip/hip_runtime.h>
#include <hip/hip_fp16.h>

#define HH 540
#define WW 960
#define HWPIX (HH*WW)   // 518400

typedef _Float16 f16;
typedef f16  f16x8 __attribute__((ext_vector_type(8)));
typedef float f32x4 __attribute__((ext_vector_type(4)));

// ---------------------------------------------------------------- conv1
// 1->64, 5x5, pad 2, PReLU. fp32 VALU (K=25, not MFMA-shaped). Unchanged.
__global__ __launch_bounds__(256) void conv1_k(const float* __restrict__ xin,
        const float* __restrict__ wg, const float* __restrict__ bg,
        const float* __restrict__ pa, f16* __restrict__ f1) {
    __shared__ float lw[25*64];
    __shared__ float lb[64];
    const int tid = threadIdx.x;
    for (int i = tid; i < 25*64; i += 256) {
        int t = i >> 6, co = i & 63;
        lw[i] = wg[co*25 + t];
    }
    if (tid < 64) lb[tid] = bg[tid];
    __syncthreads();
    int idx = blockIdx.x*256 + tid;
    if (idx >= HWPIX) return;
    const float alpha = pa[0];
    int y = idx / WW, x = idx - y*WW;
    float patch[25];
#pragma unroll
    for (int ky = 0; ky < 5; ky++) {
        int yy = y + ky - 2;
        bool yok = (unsigned)yy < (unsigned)HH;
#pragma unroll
        for (int kx = 0; kx < 5; kx++) {
            int xx = x + kx - 2;
            patch[ky*5+kx] = (yok && (unsigned)xx < (unsigned)WW) ? xin[yy*WW + xx] : 0.f;
        }
    }
    float acc[64];
#pragma unroll
    for (int c = 0; c < 64; c++) acc[c] = lb[c];
#pragma unroll
    for (int t = 0; t < 25; t++) {
        float p = patch[t];
        const float4* wv = reinterpret_cast<const float4*>(&lw[t*64]);
#pragma unroll
        for (int q = 0; q < 16; q++) {
            float4 w4 = wv[q];
            acc[q*4+0] += p*w4.x; acc[q*4+1] += p*w4.y;
            acc[q*4+2] += p*w4.z; acc[q*4+3] += p*w4.w;
        }
    }
    f16 hb[64];
#pragma unroll
    for (int c = 0; c < 64; c++) {
        float v = acc[c];
        v = (v >= 0.f) ? v : alpha*v;
        hb[c] = (f16)v;
    }
    uint4* dst = reinterpret_cast<uint4*>(f1 + (size_t)idx*64);
    const uint4* src = reinterpret_cast<const uint4*>(hb);
#pragma unroll
    for (int i = 0; i < 8; i++) dst[i] = src[i];
}

// ---------------------------------------------------------------- conv2/conv3 (MFMA)
// CI->32, 3x3, pad1, PReLU. Block = 4 rows x 64 px, 4 waves (wave w -> row w).
// mfma_f32_16x16x32_f16: wave tile = 16px x 32co (2 n-tiles), 4 m-tiles/wave.
// B-frags register-resident; A streamed from LDS tile (halo zero-padded).
template<int CI, int CIP, int MINW>
__global__ __launch_bounds__(256, MINW) void convM_k(const f16* __restrict__ fin,
        const float* __restrict__ wg, const float* __restrict__ bg,
        const float* __restrict__ pa, f16* __restrict__ fout) {
    constexpr int KC = CI/32;
    constexpr int IN_H = 6*66*CIP;            // input tile halves
    constexpr int W_H  = 9*32*CI;             // weight halves
    constexpr int SMEM_H = (IN_H > W_H ? IN_H : W_H);
    __shared__ __align__(16) f16 smem[SMEM_H];

    const int tid  = threadIdx.x;
    const int w    = tid >> 6;
    const int lane = tid & 63;
    const int l16  = lane & 15;
    const int quad = lane >> 4;               // 0..3
    const int tile = blockIdx.x;
    const int trow = tile / 15, tcol = tile - trow*15;
    const int ytile = trow*4, x0 = tcol*64;

    // 1) weights -> LDS as [tap][co][ci] fp16
    for (int i = tid; i < 9*32*CI; i += 256) {
        int ci = i % CI; int rest = i / CI; int co = rest & 31; int tap = rest >> 5;
        smem[i] = (f16)wg[(co*CI + ci)*9 + tap];
    }
    __syncthreads();
    // 2) B-frags to registers: B[k=ci][n=co], lane: n=l16(+16t), k=kc*32+quad*8+j
    f16x8 Bf[9][KC][2];
#pragma unroll
    for (int tap = 0; tap < 9; tap++)
#pragma unroll
        for (int kc = 0; kc < KC; kc++)
#pragma unroll
            for (int t = 0; t < 2; t++)
                Bf[tap][kc][t] = *(const f16x8*)&smem[(tap*32 + t*16 + l16)*CI + kc*32 + quad*8];
    const float bias0 = bg[l16], bias1 = bg[16 + l16];
    const float alpha = pa[0];
    __syncthreads();
    // 3) input tile -> LDS: rows ytile-1..ytile+4, x x0-1..x0+64, zero halo
    for (int i = tid; i < 6*66*(CI/8); i += 256) {
        int c8 = i % (CI/8); int rest = i/(CI/8); int xl = rest % 66; int r = rest/66;
        int gy = ytile + r - 1, gx = x0 + xl - 1;
        uint4 v = make_uint4(0u,0u,0u,0u);
        if ((unsigned)gy < (unsigned)HH && (unsigned)gx < (unsigned)WW)
            v = *(const uint4*)&fin[((size_t)gy*WW + gx)*CI + c8*8];
        *(uint4*)&smem[(r*66 + xl)*CIP + c8*8] = v;
    }
    __syncthreads();
    // 4) MFMA main loop
    f32x4 acc[4][2];
#pragma unroll
    for (int mt = 0; mt < 4; mt++) {
        acc[mt][0] = (f32x4){bias0,bias0,bias0,bias0};
        acc[mt][1] = (f32x4){bias1,bias1,bias1,bias1};
    }
#pragma unroll
    for (int mt = 0; mt < 4; mt++) {
#pragma unroll
        for (int dy = 0; dy < 3; dy++) {
            const f16* base = &smem[((w+dy)*66 + mt*16 + l16)*CIP + quad*8];
#pragma unroll
            for (int kc = 0; kc < KC; kc++)
#pragma unroll
                for (int dx = 0; dx < 3; dx++) {
                    f16x8 a = *(const f16x8*)&base[dx*CIP + kc*32];
                    acc[mt][0] = __builtin_amdgcn_mfma_f32_16x16x32_f16(a, Bf[dy*3+dx][kc][0], acc[mt][0], 0,0,0);
                    acc[mt][1] = __builtin_amdgcn_mfma_f32_16x16x32_f16(a, Bf[dy*3+dx][kc][1], acc[mt][1], 0,0,0);
                }
        }
    }
    __syncthreads();
    // 5) PReLU + repack to LDS [px][32] fp16 (C/D: col=l16, row=quad*4+r4)
#pragma unroll
    for (int mt = 0; mt < 4; mt++)
#pragma unroll
        for (int t = 0; t < 2; t++)
#pragma unroll
            for (int r4 = 0; r4 < 4; r4++) {
                float v = acc[mt][t][r4];
                v = (v >= 0.f) ? v : alpha*v;
                smem[(w*64 + mt*16 + quad*4 + r4)*32 + t*16 + l16] = (f16)v;
            }
    __syncthreads();
    // 6) coalesced 16B stores
    for (int i = tid; i < 1024; i += 256) {
        int px = i >> 2, c8 = i & 3;
        int r = px >> 6, xx = px & 63;
        *(uint4*)&fout[((size_t)(ytile + r)*WW + x0 + xx)*32 + c8*8] =
            *(const uint4*)&smem[px*32 + c8*8];
    }
}

// ---------------------------------------------------------------- conv4 (MFMA) + head
// 32->37 (padded to 48 = 3 n-tiles), 3x3, pad1, bias, no act; fused pixel head.
__global__ __launch_bounds__(256, 2) void conv4m_k(const f16* __restrict__ fin,
        const float* __restrict__ wg, const float* __restrict__ bg,
        float* __restrict__ outp) {
    constexpr int CI = 32, CIP = 40;
    constexpr int IN_H = 6*66*CIP;            // 15840 halves
    constexpr int W_H  = 9*48*32;             // 13824 halves
    constexpr int O_H  = 256*40*2;            // 20480 halves (fp32 olds)
    constexpr int SMEM_H = (O_H > IN_H ? O_H : IN_H);
    __shared__ __align__(16) f16 smem[SMEM_H];

    const int tid  = threadIdx.x;
    const int w    = tid >> 6;
    const int lane = tid & 63;
    const int l16  = lane & 15;
    const int quad = lane >> 4;
    const int tile = blockIdx.x;
    const int trow = tile / 15, tcol = tile - trow*15;
    const int ytile = trow*4, x0 = tcol*64;

    // 1) weights -> LDS [tap][48co][32ci], co>=37 zero
    for (int i = tid; i < W_H; i += 256) {
        int ci = i & 31; int rest = i >> 5; int co = rest % 48; int tap = rest / 48;
        smem[i] = (f16)((co < 37) ? wg[(co*32 + ci)*9 + tap] : 0.f);
    }
    __syncthreads();
    f16x8 Bf[9][3];
#pragma unroll
    for (int tap = 0; tap < 9; tap++)
#pragma unroll
        for (int t = 0; t < 3; t++)
            Bf[tap][t] = *(const f16x8*)&smem[(tap*48 + t*16 + l16)*32 + quad*8];
    float biasv[3];
#pragma unroll
    for (int t = 0; t < 3; t++) {
        int co = t*16 + l16;
        biasv[t] = (co < 37) ? bg[co] : 0.f;
    }
    __syncthreads();
    // 2) input tile -> LDS
    for (int i = tid; i < 6*66*4; i += 256) {
        int c8 = i & 3; int rest = i >> 2; int xl = rest % 66; int r = rest/66;
        int gy = ytile + r - 1, gx = x0 + xl - 1;
        uint4 v = make_uint4(0u,0u,0u,0u);
        if ((unsigned)gy < (unsigned)HH && (unsigned)gx < (unsigned)WW)
            v = *(const uint4*)&fin[((size_t)gy*WW + gx)*32 + c8*8];
        *(uint4*)&smem[(r*66 + xl)*CIP + c8*8] = v;
    }
    __syncthreads();
    // 3) MFMA
    f32x4 acc[4][3];
#pragma unroll
    for (int mt = 0; mt < 4; mt++)
#pragma unroll
        for (int t = 0; t < 3; t++)
            acc[mt][t] = (f32x4){biasv[t],biasv[t],biasv[t],biasv[t]};
#pragma unroll
    for (int mt = 0; mt < 4; mt++) {
#pragma unroll
        for (int dy = 0; dy < 3; dy++) {
            const f16* base = &smem[((w+dy)*66 + mt*16 + l16)*CIP + quad*8];
#pragma unroll
            for (int dx = 0; dx < 3; dx++) {
                f16x8 a = *(const f16x8*)&base[dx*CIP];
#pragma unroll
                for (int t = 0; t < 3; t++)
                    acc[mt][t] = __builtin_amdgcn_mfma_f32_16x16x32_f16(a, Bf[dy*3+dx][t], acc[mt][t], 0,0,0);
            }
        }
    }
    __syncthreads();
    // 4) write fp32 W to LDS [px][40]
    float* olds = (float*)smem;
#pragma unroll
    for (int mt = 0; mt < 4; mt++)
#pragma unroll
        for (int t = 0; t < 3; t++) {
            int co = t*16 + l16;
            if (co < 37) {
#pragma unroll
                for (int r4 = 0; r4 < 4; r4++)
                    olds[(w*64 + mt*16 + quad*4 + r4)*40 + co] = acc[mt][t][r4];
            }
        }
    __syncthreads();
    // 5) head: 1 px/thread. k0=(-.25,.25) k1=(.25,.25) k2=(-.25,-.25) k3=(.25,-.25)
    {
        int px = tid;
        int r = px >> 6, xx = px & 63;
        const float* Wp = &olds[px*40];
        float base = Wp[36];
        float o0 = base, o1 = base, o2 = base, o3 = base;
#pragma unroll
        for (int j = 0; j < 12; j++) {
            float u  = Wp[2*j];
            float v  = Wp[2*j+1];
            float w1 = Wp[24+j];
            float s = 0.25f*(u+v);
            float d = 0.25f*(v-u);
            o0 += fmaxf(d, 0.f)*w1;
            o1 += fmaxf(s, 0.f)*w1;
            o2 += fmaxf(-s, 0.f)*w1;
            o3 += fmaxf(-d, 0.f)*w1;
        }
        int gy = ytile + r, gx = x0 + xx;
        float2* r0 = (float2*)(outp + (size_t)(2*gy)*(2*WW) + 2*gx);
        float2* r1 = (float2*)(outp + (size_t)(2*gy+1)*(2*WW) + 2*gx);
        *r0 = make_float2(o0, o1);
        *r1 = make_float2(o2, o3);
    }
}

extern "C" void kernel_launch(void* const* d_in, const int* in_sizes, int n_in,
                              void* d_out, int out_size, void* d_ws, size_t ws_size,
                              hipStream_t stream) {
    const float* x  = (const float*)d_in[0];
    const float* w1 = (const float*)d_in[1];
    const float* b1 = (const float*)d_in[2];
    const float* w2 = (const float*)d_in[3];
    const float* b2 = (const float*)d_in[4];
    const float* w3 = (const float*)d_in[5];
    const float* b3 = (const float*)d_in[6];
    const float* w4 = (const float*)d_in[7];
    const float* b4 = (const float*)d_in[8];
    const float* pa = (const float*)d_in[9];
    float* outp = (float*)d_out;

    char* ws = (char*)d_ws;
    f16* f1 = (f16*)(ws);                            // 66,355,200 B
    f16* f2 = (f16*)(ws + 66355200);                 // 33,177,600 B
    f16* f3 = (f16*)(ws + 66355200 + 33177600);      // 33,177,600 B

    const int NT = 2025;   // (540/4) * (960/64)
    for (int b = 0; b < 4; b++) {
        conv1_k<<<dim3((HWPIX + 255)/256), 256, 0, stream>>>(
            x + (size_t)b*HWPIX, w1, b1, pa, f1);
        convM_k<64,72,2><<<dim3(NT), 256, 0, stream>>>(f1, w2, b2, pa, f2);
        convM_k<32,40,3><<<dim3(NT), 256, 0, stream>>>(f2, w3, b3, pa, f3);
        conv4m_k<<<dim3(NT), 256, 0, stream>>>(f3, w4, b4, outp + (size_t)b*4*HWPIX);
    }
}